// Round 18
// baseline (282.212 us; speedup 1.0000x reference)
//
#include <hip/hip_runtime.h>

// ---------------------------------------------------------------------------
// LRU single step, fused — v19 (v18 packed weights + v9 phase fusion retry).
//   state = Lambda * x0 + Bn @ u              (complex; stored PLANAR re|im)
//   y     = s_re @ C_re^T - s_im @ C_im^T + u @ D^T
//
// Ladder: v2 192. v7 195. v10/v14 176 (nt-loads; occupancy null).
//  v8/v11/v15/v17 scheduling/depth NULL. v12/v13/v16 REGRESS.
//  v18 100.5us WIN (-43%): fragment-packed weights -> each weight load is
//  ONE 1KB coalesced transaction (was a 16-row gather = 16 serialized L2
//  requests -- the latency multiplier every depth-lever failed against).
// v19: remaining cost = 9 serial GEMM phases x load-latency ramp. Fuse
//  y-GEMM(s) || GEMM-A(s+1) (v9 retry -- v9's regression was confounded by
//  gather addressing + VGPR squeeze, both fixed by packing): phases 9->5,
//  each fused phase = 32 coalesced loads + 8 independent MFMA chains.
//  x0 prefetch for epi(s+1) at fused-phase top (full dual-GEMM of cover).
// Kept: nt-loads, linear I/O, swapped-operand MFMA, dbuf Sc, packed W1/Wy.
// ---------------------------------------------------------------------------

typedef __attribute__((ext_vector_type(8))) short bf16x8;
typedef __attribute__((ext_vector_type(4))) float f32x4;
typedef unsigned short u16;

#define N_ROWS 32768
#define IN_DIM 256
#define SD 512
#define OUT_DIM 256
#define ROWS 32          // rows (n) per block
#define NTHR 512         // 8 waves
#define TP 264           // tile pitch in u16 (256 + 8 pad)
#define YP 260           // y staging pitch in f32
#define SMEM_U16 (3 * ROWS * TP)   // 50,688 B

#define MFMA16(a, b, c) __builtin_amdgcn_mfma_f32_16x16x32_bf16(a, b, c, 0, 0, 0)

__device__ __align__(16) float g_lam[2 * SD];            // lam_re | lam_im
// fragment-packed: [(phase*8+wv)*2+ht][kk][lane][8]
//   u16 offset = (phase*8+wv)*8192 + ht*4096 + kk*512 + lane*8
__device__ __align__(16) u16   g_W1[1024 * IN_DIM];      // 512 KB
__device__ __align__(16) u16   g_Wy[OUT_DIM * 1280];     // 640 KB (p=0..4)

__device__ __forceinline__ u16 f2b(float f) {
    union { float f; unsigned int u; } v; v.f = f;
    unsigned int r = v.u + 0x7FFFu + ((v.u >> 16) & 1u);   // RNE
    return (u16)(r >> 16);
}
__device__ __forceinline__ ushort4 f2b4(f32x4 v) {
    ushort4 b;
    b.x = f2b(v[0]); b.y = f2b(v[1]); b.z = f2b(v[2]); b.w = f2b(v[3]);
    return b;
}
__device__ __forceinline__ f32x4 b2f4(ushort4 b) {
    union { float f; unsigned int u; } t0, t1, t2, t3;
    t0.u = (unsigned)b.x << 16; t1.u = (unsigned)b.y << 16;
    t2.u = (unsigned)b.z << 16; t3.u = (unsigned)b.w << 16;
    return f32x4{t0.f, t1.f, t2.f, t3.f};
}

// --- combined prep (single launch) -----------------------------------------
__global__ void prep_all(const float* __restrict__ nu_log,
                         const float* __restrict__ theta_log,
                         const float* __restrict__ gamma_log,
                         const float* __restrict__ B_re, const float* __restrict__ B_im,
                         const float* __restrict__ C_re, const float* __restrict__ C_im,
                         const float* __restrict__ D) {
    int b = blockIdx.x, t = threadIdx.x;
    if (b < 1024) {
        // source semantics = v14 chunked-planar; destination fragment-packed.
        int s = b >> 8, q = b & 255;
        int wv = q >> 5, ht = (q >> 4) & 1, l16r = q & 15;
        int kk = t >> 5, quad = (t >> 3) & 3, e = t & 7;
        int j = q & 127;
        int h = s * 128 + j;
        float g = expf(gamma_log[h]);
        const float* src = (q < 128) ? B_re : B_im;
        size_t dst = ((((size_t)(s * 8 + wv) * 2 + ht) * 8 + kk) * 64
                      + quad * 16 + l16r) * 8 + e;
        g_W1[dst] = f2b(src[h * IN_DIM + t] * g);
    } else if (b < 1280) {
        int o = b - 1024;
        int wv2 = o >> 5, ot = (o >> 4) & 1, l16o = o & 15;
        #pragma unroll
        for (int it = 0; it < 5; ++it) {
            int c = it * 256 + t;
            int p = c >> 8, k = c & 255;
            int kk = k >> 5, quad = (k >> 3) & 3, e = k & 7;
            float v;
            if (p < 4) {
                v = (k < 128) ? C_re[o * SD + p * 128 + k]
                              : -C_im[o * SD + p * 128 + (k - 128)];
            } else {
                v = D[o * IN_DIM + k];
            }
            size_t dst = ((((size_t)(p * 8 + wv2) * 2 + ot) * 8 + kk) * 64
                          + quad * 16 + l16o) * 8 + e;
            g_Wy[dst] = f2b(v);
        }
    } else {
        int h = (b - 1280) * 256 + t;          // [0,512)
        float mod = expf(-expf(nu_log[h]));
        float th  = expf(theta_log[h]);
        g_lam[h]      = mod * cosf(th);
        g_lam[SD + h] = mod * sinf(th);
    }
}

// --- main fused kernel ------------------------------------------------------
__global__ __launch_bounds__(NTHR, 4) void lru_main(
    const float* __restrict__ u, const float* __restrict__ x0_re,
    const float* __restrict__ x0_im,
    float* __restrict__ y_out, float* __restrict__ st_out,
    long long st_limit)     // floats available in the state region of d_out
{
    __shared__ __align__(16) u16 SMEM[SMEM_U16];   // 50,688 B

    u16* Xu  = SMEM;                  // u tile bf16 [32][TP]
    u16* Sc0 = SMEM + ROWS * TP;      // state chunk bf16, ping
    u16* Sc1 = SMEM + 2 * ROWS * TP;  // state chunk bf16, pong

    const int tid  = threadIdx.x;
    const int wv   = tid >> 6;          // [0,8)
    const int lane = tid & 63;
    const int quad = lane >> 4;
    const int l16  = lane & 15;
    const int kq   = quad * 8;
    const size_t n0 = (size_t)blockIdx.x * ROWS;

    const int Mb = wv * 32;             // wave's M base within a 256-col chunk

    // linear epilogue / prefetch mapping: 1024 slots (32 rows x 32 j4)
    int en[2], ej[2];
    #pragma unroll
    for (int it = 0; it < 2; ++it) {
        int flat = it * NTHR + tid;
        en[it] = flat >> 5; ej[it] = flat & 31;
    }

    // prefetch x0 chunk 0 (nt: evict-first, don't thrash weight lines)
    f32x4 xr[2], xi[2];
    #pragma unroll
    for (int it = 0; it < 2; ++it) {
        size_t roff = (n0 + en[it]) * SD + ej[it] * 4;
        xr[it] = __builtin_nontemporal_load((const f32x4*)(x0_re + roff));
        xi[it] = __builtin_nontemporal_load((const f32x4*)(x0_im + roff));
    }

    // stage u tile -> bf16 LDS (32x256, linear nt f32x4 loads)
    #pragma unroll
    for (int i = 0; i < 4; ++i) {
        int it = tid + i * NTHR;              // 2048 items
        int r = it >> 6, c4 = it & 63;
        f32x4 v = __builtin_nontemporal_load(
            (const f32x4*)(u + (n0 + r) * IN_DIM) + c4);
        *(ushort4*)(&Xu[r * TP + c4 * 4]) = f2b4(v);
    }
    __syncthreads();

    // epilogue: in-place Sc update (chunk c) + contiguous f32 state stores
    auto epi = [&](u16* Sc, int c) {
        #pragma unroll
        for (int it = 0; it < 2; ++it) {
            const int n = en[it], j = ej[it];
            f32x4 br  = b2f4(*(const ushort4*)(&Sc[n * TP + j * 4]));
            f32x4 bi  = b2f4(*(const ushort4*)(&Sc[n * TP + 128 + j * 4]));
            f32x4 lre = *(const f32x4*)(g_lam + c * 128 + j * 4);
            f32x4 lim = *(const f32x4*)(g_lam + SD + c * 128 + j * 4);
            f32x4 sr = lre * xr[it] - lim * xi[it] + br;
            f32x4 si = lre * xi[it] + lim * xr[it] + bi;
            const long long ir = (long long)((n0 + n) * SD + c * 128 + j * 4);
            const long long ii = (long long)N_ROWS * SD + ir;
            if (ir + 3 < st_limit) {
                *(f32x4*)(st_out + ir) = sr;       // cacheable: L3 absorbs
            } else {
                #pragma unroll
                for (int k = 0; k < 4; ++k)
                    if (ir + k < st_limit) st_out[ir + k] = sr[k];
            }
            if (ii + 3 < st_limit) {
                *(f32x4*)(st_out + ii) = si;
            } else {
                #pragma unroll
                for (int k = 0; k < 4; ++k)
                    if (ii + k < st_limit) st_out[ii + k] = si[k];
            }
            *(ushort4*)(&Sc[n * TP + j * 4])       = f2b4(sr);
            *(ushort4*)(&Sc[n * TP + 128 + j * 4]) = f2b4(si);
        }
    };

    f32x4 accy[2][2];
    #pragma unroll
    for (int ot = 0; ot < 2; ++ot)
        #pragma unroll
        for (int nt = 0; nt < 2; ++nt)
            accy[ot][nt] = f32x4{0.f, 0.f, 0.f, 0.f};

    // ---- GEMM-A(0) standalone: Sc0 = W1(0) @ Xu^T (packed loads) ---------
    {
        f32x4 accA[2][2];
        #pragma unroll
        for (int ht = 0; ht < 2; ++ht)
            #pragma unroll
            for (int nt = 0; nt < 2; ++nt)
                accA[ht][nt] = f32x4{0.f, 0.f, 0.f, 0.f};
        const u16* wA = g_W1 + (size_t)(0 * 8 + wv) * 8192 + lane * 8;
        #pragma unroll
        for (int kk = 0; kk < 8; ++kk) {
            bf16x8 a[2], b[2];
            #pragma unroll
            for (int ht = 0; ht < 2; ++ht)
                a[ht] = *(const bf16x8*)(wA + ht * 4096 + kk * 512);
            #pragma unroll
            for (int nt = 0; nt < 2; ++nt)
                b[nt] = *(const bf16x8*)(&Xu[(nt * 16 + l16) * TP + kk * 32 + kq]);
            accA[0][0] = MFMA16(a[0], b[0], accA[0][0]);
            accA[0][1] = MFMA16(a[0], b[1], accA[0][1]);
            accA[1][0] = MFMA16(a[1], b[0], accA[1][0]);
            accA[1][1] = MFMA16(a[1], b[1], accA[1][1]);
        }
        #pragma unroll
        for (int ht = 0; ht < 2; ++ht)
            #pragma unroll
            for (int nt = 0; nt < 2; ++nt) {
                const int n  = nt * 16 + l16;
                const int hM = Mb + ht * 16 + quad * 4;
                *(ushort4*)(&Sc0[n * TP + hM]) = f2b4(accA[ht][nt]);
            }
    }
    __syncthreads();

    epi(Sc0, 0);
    __syncthreads();

    // ---- main loop: fused [ y-GEMM(s) || GEMM-A(s+1) ], then epi(s+1) ----
    for (int s = 0; s < 3; ++s) {
        u16* Scc = (s & 1) ? Sc1 : Sc0;       // chunk s   (bf16 state)
        u16* Scn = (s & 1) ? Sc0 : Sc1;       // chunk s+1 (Bu target)

        // prefetch x0 for epi(s+1): a full dual-GEMM phase of latency cover
        #pragma unroll
        for (int it = 0; it < 2; ++it) {
            size_t roff = (n0 + en[it]) * SD + (s + 1) * 128 + ej[it] * 4;
            xr[it] = __builtin_nontemporal_load((const f32x4*)(x0_re + roff));
            xi[it] = __builtin_nontemporal_load((const f32x4*)(x0_im + roff));
        }

        f32x4 accA[2][2];
        #pragma unroll
        for (int ht = 0; ht < 2; ++ht)
            #pragma unroll
            for (int nt = 0; nt < 2; ++nt)
                accA[ht][nt] = f32x4{0.f, 0.f, 0.f, 0.f};
        const u16* wA = g_W1 + (size_t)((s + 1) * 8 + wv) * 8192 + lane * 8;
        const u16* wY = g_Wy + (size_t)(s * 8 + wv) * 8192 + lane * 8;

        #pragma unroll
        for (int kk = 0; kk < 8; ++kk) {
            bf16x8 aA[2], aY[2], bA[2], bY[2];
            #pragma unroll
            for (int ht = 0; ht < 2; ++ht) {
                aA[ht] = *(const bf16x8*)(wA + ht * 4096 + kk * 512);
                aY[ht] = *(const bf16x8*)(wY + ht * 4096 + kk * 512);
            }
            #pragma unroll
            for (int nt = 0; nt < 2; ++nt) {
                bA[nt] = *(const bf16x8*)(&Xu[(nt * 16 + l16) * TP + kk * 32 + kq]);
                bY[nt] = *(const bf16x8*)(&Scc[(nt * 16 + l16) * TP + kk * 32 + kq]);
            }
            // two independent streams: 8 accumulator chains
            accA[0][0] = MFMA16(aA[0], bA[0], accA[0][0]);
            accy[0][0] = MFMA16(aY[0], bY[0], accy[0][0]);
            accA[0][1] = MFMA16(aA[0], bA[1], accA[0][1]);
            accy[0][1] = MFMA16(aY[0], bY[1], accy[0][1]);
            accA[1][0] = MFMA16(aA[1], bA[0], accA[1][0]);
            accy[1][0] = MFMA16(aY[1], bY[0], accy[1][0]);
            accA[1][1] = MFMA16(aA[1], bA[1], accA[1][1]);
            accy[1][1] = MFMA16(aY[1], bY[1], accy[1][1]);
        }
        // fragments -> Scn as bf16 (contiguous ushort4)
        #pragma unroll
        for (int ht = 0; ht < 2; ++ht)
            #pragma unroll
            for (int nt = 0; nt < 2; ++nt) {
                const int n  = nt * 16 + l16;
                const int hM = Mb + ht * 16 + quad * 4;
                *(ushort4*)(&Scn[n * TP + hM]) = f2b4(accA[ht][nt]);
            }
        __syncthreads();            // Scn (Bu bf16) complete; Scc readers done

        epi(Scn, s + 1);
        __syncthreads();            // Scn now bf16 state chunk
    }

    // ---- final fused: y-GEMM(3) from Sc1 || D-GEMM from Xu ---------------
    {
        const u16* wY = g_Wy + (size_t)(3 * 8 + wv) * 8192 + lane * 8;
        const u16* wD = g_Wy + (size_t)(4 * 8 + wv) * 8192 + lane * 8;
        #pragma unroll
        for (int kk = 0; kk < 8; ++kk) {
            bf16x8 aY[2], aD[2], bY[2], bU[2];
            #pragma unroll
            for (int ht = 0; ht < 2; ++ht) {
                aY[ht] = *(const bf16x8*)(wY + ht * 4096 + kk * 512);
                aD[ht] = *(const bf16x8*)(wD + ht * 4096 + kk * 512);
            }
            #pragma unroll
            for (int nt = 0; nt < 2; ++nt) {
                bY[nt] = *(const bf16x8*)(&Sc1[(nt * 16 + l16) * TP + kk * 32 + kq]);
                bU[nt] = *(const bf16x8*)(&Xu[(nt * 16 + l16) * TP + kk * 32 + kq]);
            }
            accy[0][0] = MFMA16(aY[0], bY[0], accy[0][0]);
            accy[0][1] = MFMA16(aY[0], bY[1], accy[0][1]);
            accy[1][0] = MFMA16(aY[1], bY[0], accy[1][0]);
            accy[1][1] = MFMA16(aY[1], bY[1], accy[1][1]);
            accy[0][0] = MFMA16(aD[0], bU[0], accy[0][0]);
            accy[0][1] = MFMA16(aD[0], bU[1], accy[0][1]);
            accy[1][0] = MFMA16(aD[1], bU[0], accy[1][0]);
            accy[1][1] = MFMA16(aD[1], bU[1], accy[1][1]);
        }
    }

    // ---- y: fragments -> f32 LDS (all tiles dead) -> linear store
    __syncthreads();                // everyone done reading Xu/Sc0/Sc1
    float* Yf = (float*)SMEM;       // [32][YP]  (33,280 <= 50,688)
    #pragma unroll
    for (int ot = 0; ot < 2; ++ot)
        #pragma unroll
        for (int nt = 0; nt < 2; ++nt) {
            const int n   = nt * 16 + l16;
            const int col = Mb + ot * 16 + quad * 4;
            *(f32x4*)(&Yf[n * YP + col]) = accy[ot][nt];
        }
    __syncthreads();
    #pragma unroll
    for (int i = 0; i < 4; ++i) {
        int it = tid + i * NTHR;                  // 2048 items
        int r = it >> 6, c4 = it & 63;
        f32x4 v = *(const f32x4*)(&Yf[r * YP + c4 * 4]);
        *(f32x4*)(y_out + (n0 + r) * OUT_DIM + c4 * 4) = v;
    }
}

extern "C" void kernel_launch(void* const* d_in, const int* in_sizes, int n_in,
                              void* d_out, int out_size, void* d_ws, size_t ws_size,
                              hipStream_t stream) {
    const float* u         = (const float*)d_in[0];
    const float* x0_re     = (const float*)d_in[1];
    const float* x0_im     = (const float*)d_in[2];
    const float* nu_log    = (const float*)d_in[3];
    const float* theta_log = (const float*)d_in[4];
    const float* gamma_log = (const float*)d_in[5];
    const float* B_re      = (const float*)d_in[6];
    const float* B_im      = (const float*)d_in[7];
    const float* C_re      = (const float*)d_in[8];
    const float* C_im      = (const float*)d_in[9];
    const float* D         = (const float*)d_in[10];

    float* y_out  = (float*)d_out;
    float* st_out = y_out + (size_t)N_ROWS * OUT_DIM;
    long long st_limit = (long long)out_size - (long long)N_ROWS * OUT_DIM;

    prep_all<<<1282, 256, 0, stream>>>(nu_log, theta_log, gamma_log,
                                       B_re, B_im, C_re, C_im, D);
    lru_main<<<N_ROWS / ROWS, NTHR, 0, stream>>>(u, x0_re, x0_im,
                                                 y_out, st_out, st_limit);
}